// Round 14
// baseline (44.748 us; speedup 1.0000x reference)
//
#include <hip/hip_runtime.h>

#define NCODES 512
#define DIM 128
#define NROWS (64*2048)          // 131072
#define QN (NROWS*DIM)           // 16777216
#define BLK_ROWS 128
#define NBLOCKS (NROWS/BLK_ROWS) // 1024
#define NWAVES 8                 // 512 threads, 16 rows/wave

typedef __attribute__((ext_vector_type(4))) float f32x4;

#define GLOAD_LDS16(gp, lp) __builtin_amdgcn_global_load_lds( \
    (__attribute__((address_space(1))) void*)(gp), \
    (__attribute__((address_space(3))) void*)(lp), 16, 0, 0)

// ---------------- prep: fp8 codebook (frag-ordered, x512) + weights --------
// Codebook ~U(+-1/512): scaled by 512 into e4m3 normal range (exact pow2,
// folded back via m2w = -2w/512). Layout is the MFMA B-fragment order:
// slice (t,c) = 512B; lane l's 8B at slice+l*8 = code t*16+(l&15), dims
// c*32+(l>>4)*8..+7. vq_main stages LINEARLY. (Validated R13.)
__global__ void vq_prep(const float* __restrict__ emb, const float* __restrict__ scaling,
                        unsigned char* __restrict__ e8frag,
                        float* __restrict__ wv, float* __restrict__ wse,
                        float* __restrict__ wrcp) {
  int k = blockIdx.x;
  int l = threadIdx.x; // 64 lanes; dims d=2l, 2l+1
  float2 v = ((const float2*)(emb + k * DIM))[l];
  float ss = v.x * v.x + v.y * v.y;
#pragma unroll
  for (int m = 1; m < 64; m <<= 1) ss += __shfl_xor(ss, m);
  int p = __builtin_amdgcn_cvt_pk_fp8_f32(v.x * 512.0f, v.y * 512.0f, 0, false);
  int t = k >> 4, col = k & 15;
  int c = l >> 4, g = (l >> 2) & 3, jp = l & 3;
  *(unsigned short*)(e8frag + (((t * 4 + c) * 64 + g * 16 + col) << 3) + 2 * jp) =
      (unsigned short)(p & 0xFFFF);
  if (l == 0) {
    float hr = 40.0f + (float)k * (140.0f / 511.0f);
    float wt = 1.0f + scaling[k] * ((hr - 100.0f) * (1.0f / 70.0f));
    wv[k] = wt;
    wse[k] = wt * ss;        // w_k * ||e_k||^2 (exact f32)
    wrcp[k] = 1.0f / wt;
  }
}

// ---------------- main ----------------
// 1024 blocks x 512 threads (8 waves x 16 rows). Full fp8 codebook (64KB,
// no split -> no redundancy) + tables = 71.7KB -> 2 co-resident blocks/CU
// AND 2 dispatch rounds -> skew decorrelates phases (R9's proven mechanism
// without its redundancy cost): one block streams x/stores while its CU-mate
// sweeps LDS/MFMA. Packed-u32 argmin (R8+), single-batch T14 store, atomic
// loss. Sweep: linear ds_read_b64 (conflict-free) + mfma fp8 (bf16 rate).
struct SmemT {
  unsigned char frag[NCODES * DIM]; // 65536 B fp8, fragment-ordered
  float w[NCODES];
  float wse[NCODES];
  float wrcp[NCODES];
  float lossp[NWAVES];
};

__global__ __launch_bounds__(512, 4) void vq_main(
    const float* __restrict__ x,
    const float* __restrict__ emb32,
    const unsigned char* __restrict__ e8frag,
    const float* __restrict__ wv,
    const float* __restrict__ wse,
    const float* __restrict__ wrcp,
    float* __restrict__ out_q,
    float* __restrict__ out_idx,
    float* __restrict__ out_loss) {
  __shared__ SmemT sm;
  const int tid = threadIdx.x;
  const int wave = tid >> 6, lane = tid & 63;
  const int g = lane >> 4, lr = lane & 15;
  const long rowbase = (long)blockIdx.x * BLK_ROWS + wave * 16;

  // --- Issue x loads (16 rows/wave: lane lr = row, dims g*8 per chunk) ---
  float4 xv[4][2];
  {
    const float* xr = x + (rowbase + lr) * DIM + g * 8;
#pragma unroll
    for (int c = 0; c < 4; c++) {
      xv[c][0] = *(const float4*)(xr + c * 32);
      xv[c][1] = *(const float4*)(xr + c * 32 + 4);
    }
  }

  // --- Stage fp8 codebook: LINEAR global_load_lds (prep pre-ordered).
  {
#pragma unroll
    for (int i = 0; i < 8; i++) {
      int slot = i * 512 + tid;            // 16B slot 0..4095
      GLOAD_LDS16(e8frag + slot * 16, sm.frag + slot * 16);
    }
    sm.w[tid] = wv[tid]; sm.wse[tid] = wse[tid]; sm.wrcp[tid] = wrcp[tid];
  }

  // --- Convert x to fp8 A fragments + row sumsq (f32-exact S).
  long a[4];
  float sr[4];
  {
    float ss = 0.f;
#pragma unroll
    for (int c = 0; c < 4; c++) {
      float4 v0 = xv[c][0];
      float4 v1 = xv[c][1];
      ss += v0.x * v0.x + v0.y * v0.y + v0.z * v0.z + v0.w * v0.w;
      ss += v1.x * v1.x + v1.y * v1.y + v1.z * v1.z + v1.w * v1.w;
      int lo = __builtin_amdgcn_cvt_pk_fp8_f32(v0.x, v0.y, 0, false);
      lo = __builtin_amdgcn_cvt_pk_fp8_f32(v0.z, v0.w, lo, true);
      int hi = __builtin_amdgcn_cvt_pk_fp8_f32(v1.x, v1.y, 0, false);
      hi = __builtin_amdgcn_cvt_pk_fp8_f32(v1.z, v1.w, hi, true);
      a[c] = (long)(((unsigned long long)(unsigned)hi << 32) |
                    (unsigned long long)(unsigned)lo);
    }
    ss += __shfl_xor(ss, 16);
    ss += __shfl_xor(ss, 32);   // all 4 g-lanes of row lr hold full row sum
#pragma unroll
    for (int r = 0; r < 4; r++)
      sr[r] = __shfl(ss, g * 4 + r);  // ||x||^2 of C-row g*4+r
  }
  __syncthreads();  // codebook staged; LDS read-only until loss phase

  // --- Sweep 32 column tiles of 16 codes; packed-u32 running argmin.
  unsigned pmin[4];
#pragma unroll
  for (int r = 0; r < 4; r++) pmin[r] = 0xFFFFFFFFu;

  const long* __restrict__ bbase = (const long*)sm.frag + lane;
#pragma unroll 2
  for (int t = 0; t < 32; t++) {
    const unsigned code = t * 16 + lr;    // B col = lane&15
    const float wt = sm.w[code];
    const float bb = sm.wse[code];
    const float m2w = -2.0f * wt * (1.0f / 512.0f);  // undo codebook x512
    f32x4 acc = {0.f, 0.f, 0.f, 0.f};
#pragma unroll
    for (int c = 0; c < 4; c++) {
      long bf = bbase[(t * 4 + c) * 64];
      acc = __builtin_amdgcn_mfma_f32_16x16x32_fp8_fp8(a[c], bf, acc, 0, 0, 0);
    }
#pragma unroll
    for (int r = 0; r < 4; r++) {
      float v = fmaf(m2w, acc[r], fmaf(wt, sr[r], bb));
      unsigned u = (__builtin_bit_cast(unsigned, v) & 0xFFFFFE00u) | code;
      pmin[r] = min(pmin[r], u);
    }
  }

  // --- Butterfly min across the 16 lanes of each group.
#pragma unroll
  for (int m = 1; m <= 8; m <<= 1) {
#pragma unroll
    for (int r = 0; r < 4; r++) {
      unsigned o = (unsigned)__shfl_xor((int)pmin[r], m);
      pmin[r] = min(pmin[r], o);
    }
  }

  // --- T14 store: issue ALL 8 gathers (16 rows x 32 uint4 = 8 iters),
  // bookkeeping under their latency, then write.
  const uint4* __restrict__ esrc = (const uint4*)emb32;   // 32 uint4/row
  uint4* __restrict__ outu = (uint4*)out_q + rowbase * 32;
  const int col = lane & 31;
  const int hi2 = lane >> 5;                // 0: row 2it, 1: row 2it+1
  int scode[8];
#pragma unroll
  for (int it = 0; it < 8; it++) {
    const int row0 = 2 * it;                // compile-time
    int c0 = __shfl((int)pmin[row0 & 3], (row0 >> 2) * 16);
    int c1 = __shfl((int)pmin[(row0 + 1) & 3], ((row0 + 1) >> 2) * 16);
    scode[it] = (hi2 ? c1 : c0) & 511;
  }

  uint4 vbuf[8];
#pragma unroll
  for (int j = 0; j < 8; j++)
    vbuf[j] = esrc[scode[j] * 32 + col];    // in flight...

  // ...bookkeeping under gather latency: indices + per-wave loss partial.
  {
    float l0 = 0.f;
#pragma unroll
    for (int r = 0; r < 4; r++) {
      unsigned wn = pmin[r];
      int ci = (int)(wn & 511u);
      float dist = __builtin_bit_cast(float, wn & 0xFFFFFE00u);
      l0 = fmaf(dist, sm.wrcp[ci], l0);
      if (lr == 0) out_idx[rowbase + g * 4 + r] = (float)ci;
    }
    l0 += __shfl_xor(l0, 16);
    l0 += __shfl_xor(l0, 32);   // sum over the wave's 16 rows
    if (lane == 0) sm.lossp[wave] = l0;
  }

#pragma unroll
  for (int j = 0; j < 8; j++)
    outu[j * 64 + lane] = vbuf[j];

  // --- Per-block loss reduce + one atomic (1024 atomics total).
  __syncthreads();
  if (wave == 0 && lane < NWAVES) {
    float s = sm.lossp[lane];
#pragma unroll
    for (int m = 1; m < NWAVES; m <<= 1) s += __shfl_xor(s, m);
    if (lane == 0) atomicAdd(out_loss, s * (1.6f / (float)QN));
  }
}

extern "C" void kernel_launch(void* const* d_in, const int* in_sizes, int n_in,
                              void* d_out, int out_size, void* d_ws, size_t ws_size,
                              hipStream_t stream) {
  const float* x = (const float*)d_in[0];
  const float* emb = (const float*)d_in[1];
  const float* scaling = (const float*)d_in[2];

  float* out_q = (float*)d_out;
  float* out_loss = out_q + QN;
  float* out_idx = out_q + QN + 1;

  unsigned char* e8frag = (unsigned char*)d_ws;                   // 64KB
  float* wv = (float*)((char*)d_ws + NCODES * DIM);               // 2KB
  float* wse = wv + NCODES;                                       // 2KB
  float* wrcp = wse + NCODES;                                     // 2KB

  hipMemsetAsync(out_loss, 0, sizeof(float), stream);
  vq_prep<<<NCODES, 64, 0, stream>>>(emb, scaling, e8frag, wv, wse, wrcp);
  vq_main<<<NBLOCKS, 512, 0, stream>>>(x, emb, e8frag, wv, wse, wrcp,
                                       out_q, out_idx, out_loss);
}